// Round 10
// baseline (121.342 us; speedup 1.0000x reference)
//
#include <hip/hip_runtime.h>

#define IMG 128
#define PLANE (IMG * IMG)
#define VOLSZ (IMG * IMG * IMG)

typedef float f4a __attribute__((ext_vector_type(4), aligned(4)));
typedef float f2a __attribute__((ext_vector_type(2), aligned(8)));

// Setup: rank each volume's 64 crops by (s_d, idx) -> perm[v*64 + rank] = idx.
// Concurrently-scheduled blocks then process crops with adjacent s_d, so
// their input plane windows overlap and stay L2-resident.
__global__ __launch_bounds__(256) void rank_kernel(
    const int* __restrict__ starts, int* __restrict__ perm)
{
    __shared__ int keys[256];
    int t = threadIdx.x;              // 0..255 = global crop id
    int v = t >> 6;
    int j = t & 63;
    int sd = starts[t * 3];           // s_d of crop t
    keys[t] = (sd << 6) | j;          // unique keys (tie-break j)
    __syncthreads();
    int key = keys[t];
    int rank = 0;
    #pragma unroll
    for (int k = 0; k < 64; ++k)
        rank += (keys[(v << 6) + k] < key) ? 1 : 0;
    perm[(v << 6) + rank] = j;        // bijection: slot 'rank' -> crop j
}

// One block per (slot, d_o): 256 threads = 4 waves. Each lane produces TWO
// adjacent w outputs (w = 2wp, 2wp+1, wp = lane&31); half-wave selects one of
// two adjacent h rows (hsel = lane>>5). Per wave-iter: 128 outputs via 4
// dwordx4 gathers + one contiguous 512 B store. NO LDS in the main loop.
//
// dwordx4 anchor: anc = min(s_w + i0'(w0), IMG-4); s_w + i0'(w1) + 1 <=
// s_w + sz - 1 <= 127 = anc + 3, so the load covers both lerp pairs at
// offsets sigma, sigma+delta in {0,1,2}, never outside the row.
//
// Index-clamp identity: i0' = min(i0, sz-2), fr' = src - i0'; reference's
// i1-clamp only fires at fr = 0 where fr' = 1 reproduces seg[sz-1] exactly.
__global__ __launch_bounds__(256) void crop_resize_kernel(
    const float* __restrict__ x,      // (4,1,128,128,128) f32
    const int* __restrict__ sizes,    // (4,64) i32
    const int* __restrict__ starts,   // (4,64,3) i32
    const int* __restrict__ perm,     // (4,64) slot -> crop-in-volume
    float* __restrict__ out)          // (256,64,64,64) f32
{
    // XCD-chunked swizzle (16384 blocks, %8==0 -> bijective)
    int bid  = blockIdx.x;
    int swz  = (bid & 7) * 2048 + (bid >> 3);
    int v    = swz >> 12;             // volume 0..3
    int slot = (swz >> 6) & 63;       // s_d-sorted rank within volume
    int d_o  = swz & 63;
    int crop = (v << 6) + perm[(v << 6) + slot];
    int b    = v;

    int sz  = sizes[crop];            // wave-uniform -> scalar
    int s_d = starts[crop * 3 + 0];
    int s_h = starts[crop * 3 + 1];
    int s_w = starts[crop * 3 + 2];

    float szf   = (float)sz;
    float scale = szf * (1.0f / 64.0f);
    float szm1  = szf - 1.0f;
    int   szm2  = sz - 2;

    int lane = threadIdx.x & 63;
    int wid  = __builtin_amdgcn_readfirstlane((int)threadIdx.x >> 6);
    int wp   = lane & 31;
    int hsel = lane >> 5;

    auto axis = [&](int j, int& i0, float& fr) {
        float src = ((float)j + 0.5f) * scale - 0.5f;
        src = fminf(fmaxf(src, 0.0f), szm1);
        i0 = min((int)src, szm2);
        fr = src - (float)i0;
    };

    // h axis for j = lane (broadcast source)
    int ih; float fh;
    axis(lane, ih, fh);
    int ho0 = (s_h + ih) * IMG;

    // w axis for this lane's pair
    int i00, i01; float fw0, fw1;
    axis(2 * wp,     i00, fw0);
    axis(2 * wp + 1, i01, fw1);
    float omw0 = 1.0f - fw0, omw1 = 1.0f - fw1;

    // anchored load geometry
    int anc   = min(s_w + i00, IMG - 4);   // absolute column of v[0]
    int sig   = s_w + i00 - anc;           // 0..2
    int sigd  = sig + (i01 - i00);         // 0..2 (proven)
    bool a1 = (sig  >= 1), a2 = (sig  >= 2);
    bool b1 = (sigd >= 1), b2 = (sigd >= 2);

    // d axis (uniform)
    int id; float wd_;
    axis(d_o, id, wd_);
    float wd = wd_;

    const float* prow = x + (long long)b * VOLSZ + (s_d + id) * PLANE + anc;

    float* oblk = out + ((long long)crop * 64 + d_o) * 4096 + 2 * wp;

    #pragma unroll
    for (int it = 0; it < 8; ++it) {
        int hA = it * 8 + wid * 2;         // wave covers rows hA, hA+1
        int rA = __builtin_amdgcn_readlane(ho0, hA);
        int rB = __builtin_amdgcn_readlane(ho0, hA + 1);
        float wA = __int_as_float(__builtin_amdgcn_readlane(__float_as_int(fh), hA));
        float wB = __int_as_float(__builtin_amdgcn_readlane(__float_as_int(fh), hA + 1));

        int   rh = hsel ? rB : rA;
        float wh = hsel ? wB : wA;

        const float* r00 = prow + rh;              // (d0, h0)
        f4a va = *(const f4a*)(r00);               // d0 h0
        f4a vb = *(const f4a*)(r00 + IMG);         // d0 h1
        f4a vc = *(const f4a*)(r00 + PLANE);       // d1 h0
        f4a vd = *(const f4a*)(r00 + PLANE + IMG); // d1 h1

        auto wl = [&](f4a vv, float& o0, float& o1) {
            float p0 = a1 ? (a2 ? vv.z : vv.y) : vv.x;   // elem sigma
            float p1 = a1 ? (a2 ? vv.w : vv.z) : vv.y;   // sigma+1
            float q0 = b1 ? (b2 ? vv.z : vv.y) : vv.x;   // sigma+delta
            float q1 = b1 ? (b2 ? vv.w : vv.z) : vv.y;   // sigma+delta+1
            o0 = p0 * omw0 + p1 * fw0;
            o1 = q0 * omw1 + q1 * fw1;
        };
        float a0, a1v, b0, b1v, c0, c1v, d0, d1v;
        wl(va, a0, a1v);
        wl(vb, b0, b1v);
        wl(vc, c0, c1v);
        wl(vd, d0, d1v);

        float e00 = a0  + (b0  - a0)  * wh;   // d0, w0
        float e01 = a1v + (b1v - a1v) * wh;   // d0, w1
        float e10 = c0  + (d0  - c0)  * wh;   // d1, w0
        float e11 = c1v + (d1v - c1v) * wh;   // d1, w1

        f2a res;
        res.x = e00 + (e10 - e00) * wd;
        res.y = e01 + (e11 - e01) * wd;

        __builtin_nontemporal_store(res, (f2a*)(oblk + (hA + hsel) * 64));
    }
}

extern "C" void kernel_launch(void* const* d_in, const int* in_sizes, int n_in,
                              void* d_out, int out_size, void* d_ws, size_t ws_size,
                              hipStream_t stream) {
    const float* x      = (const float*)d_in[0];
    const int*   sizes  = (const int*)d_in[1];
    const int*   starts = (const int*)d_in[2];
    float*       out    = (float*)d_out;
    int*         perm   = (int*)d_ws;    // 256 ints

    rank_kernel<<<1, 256, 0, stream>>>(starts, perm);

    int blocks = 256 * 64;   // (slot, d_o)
    crop_resize_kernel<<<blocks, 256, 0, stream>>>(x, sizes, starts, perm, out);
}

// Round 11
// 101.053 us; speedup vs baseline: 1.2008x; 1.2008x over previous
//
#include <hip/hip_runtime.h>

#define IMG 128
#define PLANE (IMG * IMG)
#define VOLSZ (IMG * IMG * IMG)

typedef float f4a __attribute__((ext_vector_type(4), aligned(4)));
typedef float f2a __attribute__((ext_vector_type(2), aligned(8)));

// One block per (crop, d-pair k): outputs d_o = 2k, 2k+1. 256 threads =
// 4 waves; lane -> w-pair (wp = lane&31 covers w = 2wp, 2wp+1), half-wave
// selects h row (hsel). Input planes for the two outputs are (q0,q0+1) and
// (q1,q1+1) with Delta = q1-q0 in {0,1,2} (scale < 2): block-uniform branch
// dedups shared planes -> 4/6/8 gather loads per 256 outputs (vs 8 naive).
//
// dwordx4 anchor: anc = min(s_w + i0'(w0), IMG-4); s_w + i0'(w1)+1 <=
// s_w+sz-1 <= 127 = anc+3 -> load never leaves the row; extraction pairs at
// offsets sigma, sigma+delta in {0,1,2} via loop-invariant v_cndmask.
//
// Index-clamp identity: i0' = min(i0, sz-2), fr' = src - i0'; reference's
// i1-clamp only fires at fr = 0 where fr' = 1 reproduces seg[sz-1] exactly.
__global__ __launch_bounds__(256) void crop_resize_kernel(
    const float* __restrict__ x,      // (4,1,128,128,128) f32
    const int* __restrict__ sizes,    // (4,64) i32
    const int* __restrict__ starts,   // (4,64,3) i32
    float* __restrict__ out)          // (256,64,64,64) f32
{
    // XCD-chunked swizzle (8192 blocks, %8==0 -> bijective)
    int bid  = blockIdx.x;
    int swz  = (bid & 7) * 1024 + (bid >> 3);
    int crop = swz >> 5;              // 0..255
    int k    = swz & 31;              // d-pair; d_o = 2k, 2k+1
    int b    = crop >> 6;

    int sz  = sizes[crop];            // wave-uniform -> scalar
    int s_d = starts[crop * 3 + 0];
    int s_h = starts[crop * 3 + 1];
    int s_w = starts[crop * 3 + 2];

    float szf   = (float)sz;
    float scale = szf * (1.0f / 64.0f);
    float szm1  = szf - 1.0f;
    int   szm2  = sz - 2;

    int lane = threadIdx.x & 63;
    int wid  = __builtin_amdgcn_readfirstlane((int)threadIdx.x >> 6);
    int wp   = lane & 31;
    int hsel = lane >> 5;

    auto axis = [&](int j, int& i0, float& fr) {
        float src = ((float)j + 0.5f) * scale - 0.5f;
        src = fminf(fmaxf(src, 0.0f), szm1);
        i0 = min((int)src, szm2);
        fr = src - (float)i0;
    };

    // h axis for j = lane (broadcast source)
    int ih; float fh;
    axis(lane, ih, fh);
    int ho0 = (s_h + ih) * IMG;

    // w axis for this lane's pair
    int i00, i01; float fw0, fw1;
    axis(2 * wp,     i00, fw0);
    axis(2 * wp + 1, i01, fw1);
    float omw0 = 1.0f - fw0, omw1 = 1.0f - fw1;

    // anchored load geometry
    int anc   = min(s_w + i00, IMG - 4);
    int sig   = s_w + i00 - anc;           // 0..2
    int sigd  = sig + (i01 - i00);         // 0..2 (proven)
    bool s1 = (sig  >= 1), s2 = (sig  >= 2);
    bool t1 = (sigd >= 1), t2 = (sigd >= 2);

    // d axis for both outputs (uniform)
    int id0, id1; float wd0, wd1;
    axis(2 * k,     id0, wd0);
    axis(2 * k + 1, id1, wd1);
    int dd = id1 - id0;                    // 0..2, block-uniform

    const float* prow = x + (long long)b * VOLSZ + (s_d + id0) * PLANE + anc;

    float* orow0 = out + ((long long)crop * 64 + 2 * k) * 4096 + 2 * wp;
    float* orow1 = orow0 + 4096;

    // w-lerp both outputs from one anchored quad
    auto wl = [&](f4a v, float& o0, float& o1) {
        float p0 = s1 ? (s2 ? v.z : v.y) : v.x;
        float p1 = s1 ? (s2 ? v.w : v.z) : v.y;
        float q0 = t1 ? (t2 ? v.z : v.y) : v.x;
        float q1 = t1 ? (t2 ? v.w : v.z) : v.y;
        o0 = p0 * omw0 + p1 * fw0;
        o1 = q0 * omw1 + q1 * fw1;
    };
    // plane q at row r: load (h0,h1), w-lerp, h-lerp -> (u0,u1)
    auto planeU = [&](const float* r, int qo, float wh_, float& u0, float& u1) {
        f4a lo = *(const f4a*)(r + qo);
        f4a hi = *(const f4a*)(r + qo + IMG);
        float l0, l1, h0v, h1v;
        wl(lo, l0, l1);
        wl(hi, h0v, h1v);
        u0 = l0 + (h0v - l0) * wh_;
        u1 = l1 + (h1v - l1) * wh_;
    };

    #define ITER_HEAD                                                        \
        int hA = it * 8 + wid * 2;                                           \
        int rA = __builtin_amdgcn_readlane(ho0, hA);                         \
        int rB = __builtin_amdgcn_readlane(ho0, hA + 1);                     \
        float wA = __int_as_float(__builtin_amdgcn_readlane(__float_as_int(fh), hA));      \
        float wB = __int_as_float(__builtin_amdgcn_readlane(__float_as_int(fh), hA + 1));  \
        int   rh = hsel ? rB : rA;                                           \
        float wh = hsel ? wB : wA;                                           \
        const float* r = prow + rh;                                          \
        int so = (hA + hsel) * 64;

    if (dd == 0) {                    // planes q0, q0+1 serve both outputs
        #pragma unroll
        for (int it = 0; it < 8; ++it) {
            ITER_HEAD
            float u00, u01, u10, u11;
            planeU(r, 0,     wh, u00, u01);
            planeU(r, PLANE, wh, u10, u11);
            f2a r0, r1;
            r0.x = u00 + (u10 - u00) * wd0;  r0.y = u01 + (u11 - u01) * wd0;
            r1.x = u00 + (u10 - u00) * wd1;  r1.y = u01 + (u11 - u01) * wd1;
            __builtin_nontemporal_store(r0, (f2a*)(orow0 + so));
            __builtin_nontemporal_store(r1, (f2a*)(orow1 + so));
        }
    } else if (dd == 1) {             // planes q0, q0+1, q0+2
        #pragma unroll
        for (int it = 0; it < 8; ++it) {
            ITER_HEAD
            float u00, u01, u10, u11, u20, u21;
            planeU(r, 0,         wh, u00, u01);
            planeU(r, PLANE,     wh, u10, u11);
            planeU(r, 2 * PLANE, wh, u20, u21);
            f2a r0, r1;
            r0.x = u00 + (u10 - u00) * wd0;  r0.y = u01 + (u11 - u01) * wd0;
            r1.x = u10 + (u20 - u10) * wd1;  r1.y = u11 + (u21 - u11) * wd1;
            __builtin_nontemporal_store(r0, (f2a*)(orow0 + so));
            __builtin_nontemporal_store(r1, (f2a*)(orow1 + so));
        }
    } else {                          // planes q0, q0+1, q0+dd, q0+dd+1
        int o2 = dd * PLANE, o3 = o2 + PLANE;
        #pragma unroll
        for (int it = 0; it < 8; ++it) {
            ITER_HEAD
            float u00, u01, u10, u11, u20, u21, u30, u31;
            planeU(r, 0,     wh, u00, u01);
            planeU(r, PLANE, wh, u10, u11);
            planeU(r, o2,    wh, u20, u21);
            planeU(r, o3,    wh, u30, u31);
            f2a r0, r1;
            r0.x = u00 + (u10 - u00) * wd0;  r0.y = u01 + (u11 - u01) * wd0;
            r1.x = u20 + (u30 - u20) * wd1;  r1.y = u21 + (u31 - u21) * wd1;
            __builtin_nontemporal_store(r0, (f2a*)(orow0 + so));
            __builtin_nontemporal_store(r1, (f2a*)(orow1 + so));
        }
    }
    #undef ITER_HEAD
}

extern "C" void kernel_launch(void* const* d_in, const int* in_sizes, int n_in,
                              void* d_out, int out_size, void* d_ws, size_t ws_size,
                              hipStream_t stream) {
    const float* x      = (const float*)d_in[0];
    const int*   sizes  = (const int*)d_in[1];
    const int*   starts = (const int*)d_in[2];
    float*       out    = (float*)d_out;

    int blocks = 256 * 32;   // (crop, d-pair)
    crop_resize_kernel<<<blocks, 256, 0, stream>>>(x, sizes, starts, out);
}

// Round 12
// 90.602 us; speedup vs baseline: 1.3393x; 1.1154x over previous
//
#include <hip/hip_runtime.h>

#define IMG 128
#define PLANE (IMG * IMG)
#define VOLSZ (IMG * IMG * IMG)

typedef float f4a __attribute__((ext_vector_type(4), aligned(4)));
typedef float f2a __attribute__((ext_vector_type(2), aligned(8)));

// Plane-sweep: block = (crop, h-slice of 8 rows, d-quarter of 16 outputs).
// Sweep input planes p = id(d0)..id(d15)+1 ONCE each; per plane each lane
// computes the h/w-resampled u(p) for its (2w x 1h) footprint (2 anchored
// dwordx4 + w-lerp + h-lerp), then emits every output d with id(d) = p-1 as
// A + wd*(B-A) where A,B = u(p-1),u(p) held in registers. Input planes are
// read exactly once per block -> d-reuse lives in registers, not cache.
// Depth-1 plane prefetch hides latency; runs found via uniform __ballot.
//
// dwordx4 anchor: anc = min(s_w + i0'(w0), IMG-4); extraction offsets
// sigma, sigma+delta in {0,1,2} (proven from scale < 2) via v_cndmask.
// Index-clamp identity: i0' = min(i0, sz-2), fr' = src - i0'; reference's
// i1-clamp only fires at fr = 0 where fr' = 1 reproduces seg[sz-1] exactly.
__global__ __launch_bounds__(256) void crop_resize_kernel(
    const float* __restrict__ x,      // (4,1,128,128,128) f32
    const int* __restrict__ sizes,    // (4,64) i32
    const int* __restrict__ starts,   // (4,64,3) i32
    float* __restrict__ out)          // (256,64,64,64) f32
{
    // XCD-chunked swizzle (8192 blocks, %8==0 -> bijective)
    int bid  = blockIdx.x;
    int swz  = (bid & 7) * 1024 + (bid >> 3);
    int crop = swz >> 5;              // 0..255
    int rem  = swz & 31;
    int hsl8 = (rem >> 2) << 3;       // h-slice base row (0,8,..,56)
    int dq16 = (rem & 3) << 4;        // d-quarter base (0,16,32,48)
    int b    = crop >> 6;

    int sz  = sizes[crop];            // wave-uniform -> scalar
    int s_d = starts[crop * 3 + 0];
    int s_h = starts[crop * 3 + 1];
    int s_w = starts[crop * 3 + 2];

    float szf   = (float)sz;
    float scale = szf * (1.0f / 64.0f);
    float szm1  = szf - 1.0f;
    int   szm2  = sz - 2;

    int lane = threadIdx.x & 63;
    int wid  = __builtin_amdgcn_readfirstlane((int)threadIdx.x >> 6);
    int wp   = lane & 31;
    int hs   = lane >> 5;

    auto axis = [&](int j, int& i0, float& fr) {
        float src = ((float)j + 0.5f) * scale - 0.5f;
        src = fminf(fmaxf(src, 0.0f), szm1);
        i0 = min((int)src, szm2);
        fr = src - (float)i0;
    };

    // w axis for this lane's pair (w = 2wp, 2wp+1)
    int i00, i01; float fw0, fw1;
    axis(2 * wp,     i00, fw0);
    axis(2 * wp + 1, i01, fw1);
    float omw0 = 1.0f - fw0, omw1 = 1.0f - fw1;

    int anc  = min(s_w + i00, IMG - 4);
    int sig  = s_w + i00 - anc;            // 0..2
    int sigd = sig + (i01 - i00);          // 0..2 (proven)
    bool s1 = (sig  >= 1), s2 = (sig  >= 2);
    bool t1 = (sigd >= 1), t2 = (sigd >= 2);

    // h axis: lane fully owns its output row
    int hrow = hsl8 + wid * 2 + hs;
    int ihh; float fh;
    axis(hrow, ihh, fh);

    // d axis coords for j = dq16 + (lane&15), held in lanes 0..15 (pattern
    // repeats across 16-lane groups; ballot bits taken from low 16)
    int idj; float fdj;
    axis(dq16 + (lane & 15), idj, fdj);

    int p0   = __builtin_amdgcn_readlane(idj, 0);
    int pend = __builtin_amdgcn_readlane(idj, 15) + 1;   // >= p0+1

    // plane p row address = sp (advances by PLANE per iter)
    const float* sp = x + (long long)b * VOLSZ
                    + (s_d + p0) * PLANE + (s_h + ihh) * IMG + anc;

    // output base for this lane (d added per-store)
    float* ob = out + ((long long)crop * 64) * 4096 + hrow * 64 + 2 * wp;

    auto wl = [&](f4a v, float& o0, float& o1) {
        float p0v = s1 ? (s2 ? v.z : v.y) : v.x;
        float p1v = s1 ? (s2 ? v.w : v.z) : v.y;
        float q0v = t1 ? (t2 ? v.z : v.y) : v.x;
        float q1v = t1 ? (t2 ? v.w : v.z) : v.y;
        o0 = p0v * omw0 + p1v * fw0;
        o1 = q0v * omw1 + q1v * fw1;
    };

    f4a rlo = *(const f4a*)(sp);
    f4a rhi = *(const f4a*)(sp + IMG);

    float a0 = 0.0f, a1 = 0.0f;

    for (int p = p0; p <= pend; ++p) {
        // prefetch next plane (clamped at pend: harmless re-read, no OOB)
        const float* spn = sp + (p < pend ? PLANE : 0);
        f4a nlo = *(const f4a*)(spn);
        f4a nhi = *(const f4a*)(spn + IMG);

        // u(p) for this lane
        float l0, l1, g0, g1;
        wl(rlo, l0, l1);
        wl(rhi, g0, g1);
        float b0v = l0 + (g0 - l0) * fh;
        float b1v = l1 + (g1 - l1) * fh;

        // emit outputs whose planes are (p-1, p)
        if (p > p0) {
            unsigned long long m = __ballot(idj == (p - 1)) & 0xFFFFull;
            while (m) {
                int dr = __ffsll((unsigned long long)m) - 1;
                m &= m - 1;
                float wd = __int_as_float(
                    __builtin_amdgcn_readlane(__float_as_int(fdj), dr));
                f2a r;
                r.x = a0 + (b0v - a0) * wd;
                r.y = a1 + (b1v - a1) * wd;
                __builtin_nontemporal_store(r,
                    (f2a*)(ob + (long long)(dq16 + dr) * 4096));
            }
        }
        a0 = b0v; a1 = b1v;
        rlo = nlo; rhi = nhi;
        sp  = spn;
    }
}

extern "C" void kernel_launch(void* const* d_in, const int* in_sizes, int n_in,
                              void* d_out, int out_size, void* d_ws, size_t ws_size,
                              hipStream_t stream) {
    const float* x      = (const float*)d_in[0];
    const int*   sizes  = (const int*)d_in[1];
    const int*   starts = (const int*)d_in[2];
    float*       out    = (float*)d_out;

    int blocks = 256 * 32;   // (crop, h-slice, d-quarter)
    crop_resize_kernel<<<blocks, 256, 0, stream>>>(x, sizes, starts, out);
}

// Round 13
// 89.372 us; speedup vs baseline: 1.3577x; 1.0138x over previous
//
#include <hip/hip_runtime.h>

#define IMG 128
#define PLANE (IMG * IMG)
#define VOLSZ (IMG * IMG * IMG)

typedef float f4a __attribute__((ext_vector_type(4), aligned(4)));
typedef float f2a __attribute__((ext_vector_type(2), aligned(8)));

// Plane-sweep: block = (crop, h-slice of 8 rows, d-HALF of 32 outputs).
// Sweep input planes p = id(d0)..id(d31)+1 ONCE each; per plane each lane
// computes the h/w-resampled u(p) for its (2w x 1h) footprint (2 anchored
// dwordx4 + w-lerp + h-lerp), then emits every output d with id(d) = p-1 as
// A + wd*(B-A), A,B = u(p-1),u(p) carried in registers. Input planes are
// read exactly once per block -> d-reuse lives in registers, not cache.
// Depth-1 plane prefetch hides latency; emission runs found via __ballot.
//
// dwordx4 anchor: anc = min(s_w + i0'(w0), IMG-4); extraction offsets
// sigma, sigma+delta in {0,1,2} (proven from scale < 2) via v_cndmask.
// Index-clamp identity: i0' = min(i0, sz-2), fr' = src - i0'; reference's
// i1-clamp only fires at fr = 0 where fr' = 1 reproduces seg[sz-1] exactly.
__global__ __launch_bounds__(256) void crop_resize_kernel(
    const float* __restrict__ x,      // (4,1,128,128,128) f32
    const int* __restrict__ sizes,    // (4,64) i32
    const int* __restrict__ starts,   // (4,64,3) i32
    float* __restrict__ out)          // (256,64,64,64) f32
{
    // XCD-chunked swizzle (4096 blocks, %8==0 -> bijective)
    int bid  = blockIdx.x;
    int swz  = (bid & 7) * 512 + (bid >> 3);
    int crop = swz >> 4;              // 0..255
    int rem  = swz & 15;
    int hsl8 = (rem >> 1) << 3;       // h-slice base row (0,8,..,56)
    int dh32 = (rem & 1) << 5;        // d-half base (0,32)
    int b    = crop >> 6;

    int sz  = sizes[crop];            // wave-uniform -> scalar
    int s_d = starts[crop * 3 + 0];
    int s_h = starts[crop * 3 + 1];
    int s_w = starts[crop * 3 + 2];

    float szf   = (float)sz;
    float scale = szf * (1.0f / 64.0f);
    float szm1  = szf - 1.0f;
    int   szm2  = sz - 2;

    int lane = threadIdx.x & 63;
    int wid  = __builtin_amdgcn_readfirstlane((int)threadIdx.x >> 6);
    int wp   = lane & 31;
    int hs   = lane >> 5;

    auto axis = [&](int j, int& i0, float& fr) {
        float src = ((float)j + 0.5f) * scale - 0.5f;
        src = fminf(fmaxf(src, 0.0f), szm1);
        i0 = min((int)src, szm2);
        fr = src - (float)i0;
    };

    // w axis for this lane's pair (w = 2wp, 2wp+1)
    int i00, i01; float fw0, fw1;
    axis(2 * wp,     i00, fw0);
    axis(2 * wp + 1, i01, fw1);
    float omw0 = 1.0f - fw0, omw1 = 1.0f - fw1;

    int anc  = min(s_w + i00, IMG - 4);
    int sig  = s_w + i00 - anc;            // 0..2
    int sigd = sig + (i01 - i00);          // 0..2 (proven)
    bool s1 = (sig  >= 1), s2 = (sig  >= 2);
    bool t1 = (sigd >= 1), t2 = (sigd >= 2);

    // h axis: lane fully owns its output row
    int hrow = hsl8 + wid * 2 + hs;
    int ihh; float fh;
    axis(hrow, ihh, fh);

    // d axis coords for j = dh32 + (lane&31); pattern identical in both
    // half-waves -> ballot bits taken from the low 32
    int idj; float fdj;
    axis(dh32 + wp, idj, fdj);

    int p0   = __builtin_amdgcn_readlane(idj, 0);
    int pend = __builtin_amdgcn_readlane(idj, 31) + 1;   // >= p0+1

    // plane p row address (advances by PLANE per iter)
    const float* sp = x + (long long)b * VOLSZ
                    + (s_d + p0) * PLANE + (s_h + ihh) * IMG + anc;

    // output base for this lane (d added per-store)
    float* ob = out + ((long long)crop * 64) * 4096 + hrow * 64 + 2 * wp;

    auto wl = [&](f4a v, float& o0, float& o1) {
        float p0v = s1 ? (s2 ? v.z : v.y) : v.x;
        float p1v = s1 ? (s2 ? v.w : v.z) : v.y;
        float q0v = t1 ? (t2 ? v.z : v.y) : v.x;
        float q1v = t1 ? (t2 ? v.w : v.z) : v.y;
        o0 = p0v * omw0 + p1v * fw0;
        o1 = q0v * omw1 + q1v * fw1;
    };

    f4a rlo = *(const f4a*)(sp);
    f4a rhi = *(const f4a*)(sp + IMG);

    float a0 = 0.0f, a1 = 0.0f;

    for (int p = p0; p <= pend; ++p) {
        // prefetch next plane (clamped at pend: re-read, no OOB)
        const float* spn = sp + (p < pend ? PLANE : 0);
        f4a nlo = *(const f4a*)(spn);
        f4a nhi = *(const f4a*)(spn + IMG);

        // u(p) for this lane
        float l0, l1, g0, g1;
        wl(rlo, l0, l1);
        wl(rhi, g0, g1);
        float b0v = l0 + (g0 - l0) * fh;
        float b1v = l1 + (g1 - l1) * fh;

        // emit outputs whose planes are (p-1, p)
        if (p > p0) {
            unsigned long long m = __ballot(idj == (p - 1)) & 0xFFFFFFFFull;
            while (m) {
                int dr = __ffsll((unsigned long long)m) - 1;
                m &= m - 1;
                float wd = __int_as_float(
                    __builtin_amdgcn_readlane(__float_as_int(fdj), dr));
                f2a r;
                r.x = a0 + (b0v - a0) * wd;
                r.y = a1 + (b1v - a1) * wd;
                __builtin_nontemporal_store(r,
                    (f2a*)(ob + (long long)(dh32 + dr) * 4096));
            }
        }
        a0 = b0v; a1 = b1v;
        rlo = nlo; rhi = nhi;
        sp  = spn;
    }
}

extern "C" void kernel_launch(void* const* d_in, const int* in_sizes, int n_in,
                              void* d_out, int out_size, void* d_ws, size_t ws_size,
                              hipStream_t stream) {
    const float* x      = (const float*)d_in[0];
    const int*   sizes  = (const int*)d_in[1];
    const int*   starts = (const int*)d_in[2];
    float*       out    = (float*)d_out;

    int blocks = 256 * 16;   // (crop, h-slice, d-half)
    crop_resize_kernel<<<blocks, 256, 0, stream>>>(x, sizes, starts, out);
}